// Round 4
// baseline (183.968 us; speedup 1.0000x reference)
//
#include <hip/hip_runtime.h>

#define N_NODES 50000
#define N_EDGES 800000
#define IN_F 256
#define OUT_F 128

#define CHUNKS 128
#define EPC (N_EDGES / CHUNKS)   // 6250 edges per chunk
#define BINW (N_NODES / 4)       // 12500 u32 words, 4 x u8 bins each (50 KB LDS)
#define NWORDS (N_NODES / 4)     // 12500 packed node-words
#define RGB 196                  // reduceoff blocks: 64 words (256 nodes) each
#define HIST_BLOCKS (2 * CHUNKS) // 256
#define CPW (CHUNKS / 4)         // 32 chunks per wave

#define GEMM_BLOCKS 391          // 128 rows each -> 50048 >= 50000
#define SCAT_BLOCKS 782          // 1024 edges each -> 800768 >= 800000

typedef __attribute__((ext_vector_type(8))) short short8;
typedef __attribute__((ext_vector_type(4))) float float4_t;

// float -> bf16 round-to-nearest-even
__device__ __forceinline__ short f2bf(float f) {
  unsigned u = __builtin_bit_cast(unsigned, f);
  u = u + 0x7FFFu + ((u >> 16) & 1u);
  return (short)(u >> 16);
}

__device__ __forceinline__ float bflo(unsigned u) {
  return __builtin_bit_cast(float, u << 16);
}
__device__ __forceinline__ float bfhi(unsigned u) {
  return __builtin_bit_cast(float, u & 0xFFFF0000u);
}

// ---- histogram + per-edge rank (LDS-privatized u8 bins) + fused wprep ----
// 512 threads/block (8 waves/CU at 1 block/CU — latency hiding for key loads).
// blocks 0..255: b>>7 = side (0:dst, 1:src), b&127 = chunk. blocks 256..257: wprep.
__global__ __launch_bounds__(512) void hist_kernel(const int* __restrict__ src,
                                                   const int* __restrict__ dst,
                                                   unsigned char* __restrict__ pdst8,
                                                   unsigned char* __restrict__ psrc8,
                                                   unsigned char* __restrict__ rank8,
                                                   const float* __restrict__ W,
                                                   short* __restrict__ Wf,
                                                   int* __restrict__ cursor) {
  __shared__ unsigned bins[BINW];
  int b = blockIdx.x;
  int t = threadIdx.x;
  if (b >= HIST_BLOCKS) {  // wprep: 2 blocks cover 32768 elements; also zero cursor
    int bb = b - HIST_BLOCKS;
    if (bb == 0 && t == 0) *cursor = 0;
#pragma unroll
    for (int i = 0; i < 32; ++i) {
      int idx = bb * 16384 + i * 512 + t;
      int k = idx >> 7, n = idx & 127;
      int s = k >> 5, q = (k >> 3) & 3, j = k & 7;
      int tt = n >> 4, m = n & 15;
      Wf[(((s * 8 + tt) * 16 + m) * 32) + q * 8 + j] = f2bf(W[idx]);
    }
    return;
  }
  int h = b >> 7;
  int c = b & 127;
  uint4* b4 = (uint4*)bins;
  for (int j = t; j < BINW / 4; j += 512) b4[j] = (uint4){0u, 0u, 0u, 0u};
  __syncthreads();
  const int* key = h ? src : dst;
  int e0 = c * EPC;

  auto process = [&](int v, int eI) {
    unsigned sh = (v & 3) * 8;
    unsigned old = atomicAdd(&bins[v >> 2], 1u << sh);
    if (!h) rank8[eI] = (unsigned char)((old >> sh) & 0xFFu);
  };

  // 3 full tiles of 2048 + tail of 106 (EPC = 6250)
#pragma unroll 2
  for (int tile = 0; tile < 3; ++tile) {
    int i = tile * 2048 + t;
    int k0 = key[e0 + i];
    int k1 = key[e0 + i + 512];
    int k2 = key[e0 + i + 1024];
    int k3 = key[e0 + i + 1536];
    process(k0, e0 + i);
    process(k1, e0 + i + 512);
    process(k2, e0 + i + 1024);
    process(k3, e0 + i + 1536);
  }
  {
    int i = 6144 + t;
    if (i < EPC) process(key[e0 + i], e0 + i);
  }
  __syncthreads();
  uint4* p128 = (uint4*)((h ? psrc8 : pdst8) + (size_t)c * N_NODES);  // rows 16B-aligned (50000%16==0)
  const uint4* s128 = (const uint4*)bins;
  for (int j = t; j < BINW / 4; j += 512) p128[j] = s128[j];
}

// grid (RGB, 2). Wave-split chunk prefix with packed-byte (4-node) arithmetic.
__global__ __launch_bounds__(256) void reduceoff_kernel(const unsigned char* __restrict__ pdst8,
                                                        const unsigned char* __restrict__ psrc8,
                                                        unsigned char* __restrict__ delta8,
                                                        int* __restrict__ cnt,
                                                        int* __restrict__ row_start,
                                                        int* __restrict__ cursor,
                                                        float* __restrict__ norm) {
  __shared__ unsigned tot[4][64];
  int g = blockIdx.x, side = blockIdx.y;
  int t = threadIdx.x;
  int w = t >> 6, l = t & 63;
  int wd = g * 64 + l;
  bool ok = wd < NWORDS;
  int wdc = ok ? wd : NWORDS - 1;  // clamp for safe addressing
  const unsigned* P = (const unsigned*)(side == 0 ? pdst8 : psrc8);

  unsigned vals[CPW];
  unsigned s = 0;
#pragma unroll
  for (int i = 0; i < CPW; ++i) {
    vals[i] = P[(size_t)(w * CPW + i) * NWORDS + wdc];
    s += vals[i];
  }
  tot[w][l] = s;
  __syncthreads();

  if (side == 0) {
    unsigned base = 0;
#pragma unroll
    for (int w2 = 0; w2 < 4; ++w2)
      if (w2 < w) base += tot[w2][l];
    unsigned run = base;
    unsigned* D = (unsigned*)delta8;
    if (ok) {
#pragma unroll
      for (int i = 0; i < CPW; ++i) {
        D[(size_t)(w * CPW + i) * NWORDS + wd] = run;
        run += vals[i];
      }
    }
    if (w == 0) {
      unsigned ftot = tot[0][l] + tot[1][l] + tot[2][l] + tot[3][l];
      if (!ok) ftot = 0;
      int c0 = ftot & 255, c1 = (ftot >> 8) & 255, c2 = (ftot >> 16) & 255, c3 = ftot >> 24;
      int T = c0 + c1 + c2 + c3;
      int x = T;
#pragma unroll
      for (int off = 1; off < 64; off <<= 1) {
        int y = __shfl_up(x, off);
        if (l >= off) x += y;
      }
      int waveTotal = __shfl(x, 63);
      int sb = 0;
      if (l == 63) sb = atomicAdd(cursor, waveTotal);
      sb = __shfl(sb, 63);
      int E = sb + x - T;
      if (ok) {
        int4 cv = {c0, c1, c2, c3};
        int4 rv = {E, E + c0, E + c0 + c1, E + c0 + c1 + c2};
        ((int4*)cnt)[wd] = cv;
        ((int4*)row_start)[wd] = rv;
      }
    }
  } else {
    if (w == 0 && ok) {
      unsigned ftot = tot[0][l] + tot[1][l] + tot[2][l] + tot[3][l];
      float4 nv;
      int d0 = ftot & 255, d1 = (ftot >> 8) & 255, d2 = (ftot >> 16) & 255, d3 = (int)(ftot >> 24);
      nv.x = 1.0f / (float)(d0 > 1 ? d0 : 1);
      nv.y = 1.0f / (float)(d1 > 1 ? d1 : 1);
      nv.z = 1.0f / (float)(d2 > 1 ? d2 : 1);
      nv.w = 1.0f / (float)(d3 > 1 ? d3 : 1);
      ((float4*)norm)[wd] = nv;
    }
  }
}

// ---- GEMM only: h = (feat @ W) * norm. 4 waves x 32 rows = 128 rows/block. ----
// Split from the old fused sg_kernel so rocprof times GEMM and scatter separately.
__global__ __launch_bounds__(256) void gemm_kernel(const float* __restrict__ feat,
                                                   const short* __restrict__ Wf,
                                                   const float* __restrict__ norm,
                                                   unsigned short* __restrict__ h) {
  int b = blockIdx.x;
  int tid = threadIdx.x;
  int w = tid >> 6, l = tid & 63;
  int m = l & 15, q = l >> 4;
  long base = (long)b * 128 + w * 32;

  float4_t acc[2][8];
#pragma unroll
  for (int r = 0; r < 2; ++r)
#pragma unroll
    for (int t = 0; t < 8; ++t) acc[r][t] = (float4_t)(0.0f);

  long row0 = base + m;
  long row1 = base + 16 + m;
  long r0c = row0 < N_NODES - 1 ? row0 : N_NODES - 1;
  long r1c = row1 < N_NODES - 1 ? row1 : N_NODES - 1;
  const float* a0p = feat + (size_t)r0c * IN_F;
  const float* a1p = feat + (size_t)r1c * IN_F;
  const short8* bb = (const short8*)Wf;

#pragma unroll
  for (int s = 0; s < 8; ++s) {
    int k0 = s * 32 + q * 8;
    float4_t av0a = *(const float4_t*)(a0p + k0);
    float4_t av0b = *(const float4_t*)(a0p + k0 + 4);
    float4_t av1a = *(const float4_t*)(a1p + k0);
    float4_t av1b = *(const float4_t*)(a1p + k0 + 4);
    short8 fa0, fa1;
#pragma unroll
    for (int i = 0; i < 4; ++i) {
      fa0[i] = f2bf(av0a[i]);
      fa0[i + 4] = f2bf(av0b[i]);
      fa1[i] = f2bf(av1a[i]);
      fa1[i + 4] = f2bf(av1b[i]);
    }
#pragma unroll
    for (int t = 0; t < 8; ++t) {
      short8 fb = bb[((s * 8 + t) * 16 + m) * 4 + q];
      acc[0][t] = __builtin_amdgcn_mfma_f32_16x16x32_bf16(fa0, fb, acc[0][t], 0, 0, 0);
      acc[1][t] = __builtin_amdgcn_mfma_f32_16x16x32_bf16(fa1, fb, acc[1][t], 0, 0, 0);
    }
  }

  // C/D layout: col = lane&15 (=m), row = q*4 + i
#pragma unroll
  for (int r = 0; r < 2; ++r) {
#pragma unroll
    for (int i = 0; i < 4; ++i) {
      long row = base + r * 16 + q * 4 + i;
      if (row < N_NODES) {
        float nm = norm[row];
        size_t ho = (size_t)row * OUT_F;
#pragma unroll
        for (int t = 0; t < 8; ++t) {
          h[ho + t * 16 + m] = (unsigned short)f2bf(acc[r][t][i] * nm);
        }
      }
    }
  }
}

// ---- scatter only: stateless, 4 edges/thread. ----
__global__ __launch_bounds__(256) void scat_kernel(const int* __restrict__ src,
                                                   const int* __restrict__ dst,
                                                   const int* __restrict__ row_start,
                                                   const unsigned char* __restrict__ delta8,
                                                   const unsigned char* __restrict__ rank8,
                                                   int* __restrict__ eidx) {
  int gt = blockIdx.x * 256 + threadIdx.x;
  int e = gt * 4;
  if (e >= N_EDGES) return;
  int4 d4 = *(const int4*)(dst + e);
  int4 s4 = *(const int4*)(src + e);
  unsigned rr = *(const unsigned*)(rank8 + e);
  int dd[4] = {d4.x, d4.y, d4.z, d4.w};
  int ss[4] = {s4.x, s4.y, s4.z, s4.w};
#pragma unroll
  for (int k = 0; k < 4; ++k) {
    int c = (e + k) / EPC;
    int d = dd[k];
    int pos = row_start[d] + (int)delta8[(size_t)c * N_NODES + d] + (int)((rr >> (8 * k)) & 0xFFu);
    eidx[pos] = ss[k];
  }
}

// One wave per dst node; lane-halves cover 2 rows, 8-row unrolled gather for MLP depth.
__global__ __launch_bounds__(256) void agg_kernel(const unsigned short* __restrict__ h,
                                                  const int* __restrict__ row_start,
                                                  const int* __restrict__ cnt,
                                                  const int* __restrict__ eidx,
                                                  const float* __restrict__ bias,
                                                  float* __restrict__ out) {
  int w = threadIdx.x >> 6, l = threadIdx.x & 63;
  int d = blockIdx.x * 4 + w;  // grid 12500 -> exactly 50000
  int rs = row_start[d], re = rs + cnt[d];
  const unsigned* __restrict__ hu = (const unsigned*)h;  // 64 uints per row
  int rowsel = l >> 5, cp = l & 31;  // lane covers cols 4*cp .. 4*cp+3
  float a0 = 0.f, a1 = 0.f, a2 = 0.f, a3 = 0.f;
  for (int bse = rs; bse < re; bse += 64) {
    int n = re - bse; if (n > 64) n = 64;
    int e = (l < n) ? eidx[bse + l] : 0;
    int half = (n + 1) >> 1;
    int j = 0;
    for (; j + 4 <= half; j += 4) {  // 8 rows per iteration, 4 gathers in flight
      int i0 = 2 * j + rowsel;
      int s0 = __shfl(e, i0);
      int s1 = __shfl(e, i0 + 2);
      int s2 = __shfl(e, i0 + 4);
      int s3 = __shfl(e, i0 + 6);
      uint2 v0 = *(const uint2*)(hu + (size_t)s0 * 64 + 2 * cp);
      uint2 v1 = *(const uint2*)(hu + (size_t)s1 * 64 + 2 * cp);
      uint2 v2 = *(const uint2*)(hu + (size_t)s2 * 64 + 2 * cp);
      uint2 v3 = *(const uint2*)(hu + (size_t)s3 * 64 + 2 * cp);
      if (i0 >= n) { v0.x = 0; v0.y = 0; }
      if (i0 + 2 >= n) { v1.x = 0; v1.y = 0; }
      if (i0 + 4 >= n) { v2.x = 0; v2.y = 0; }
      if (i0 + 6 >= n) { v3.x = 0; v3.y = 0; }
      a0 += bflo(v0.x); a1 += bfhi(v0.x); a2 += bflo(v0.y); a3 += bfhi(v0.y);
      a0 += bflo(v1.x); a1 += bfhi(v1.x); a2 += bflo(v1.y); a3 += bfhi(v1.y);
      a0 += bflo(v2.x); a1 += bfhi(v2.x); a2 += bflo(v2.y); a3 += bfhi(v2.y);
      a0 += bflo(v3.x); a1 += bfhi(v3.x); a2 += bflo(v3.y); a3 += bfhi(v3.y);
    }
    for (; j + 2 <= half; j += 2) {
      int i0 = 2 * j + rowsel;
      int i1 = i0 + 2;
      int s0 = __shfl(e, i0);
      int s1 = __shfl(e, i1);
      uint2 v0 = *(const uint2*)(hu + (size_t)s0 * 64 + 2 * cp);
      uint2 v1 = *(const uint2*)(hu + (size_t)s1 * 64 + 2 * cp);
      if (i0 >= n) { v0.x = 0; v0.y = 0; }
      if (i1 >= n) { v1.x = 0; v1.y = 0; }
      a0 += bflo(v0.x); a1 += bfhi(v0.x); a2 += bflo(v0.y); a3 += bfhi(v0.y);
      a0 += bflo(v1.x); a1 += bfhi(v1.x); a2 += bflo(v1.y); a3 += bfhi(v1.y);
    }
    for (; j < half; ++j) {
      int i0 = 2 * j + rowsel;
      int s0 = __shfl(e, i0);
      uint2 v0 = *(const uint2*)(hu + (size_t)s0 * 64 + 2 * cp);
      if (i0 >= n) { v0.x = 0; v0.y = 0; }
      a0 += bflo(v0.x); a1 += bfhi(v0.x); a2 += bflo(v0.y); a3 += bfhi(v0.y);
    }
  }
  a0 += __shfl_xor(a0, 32);
  a1 += __shfl_xor(a1, 32);
  a2 += __shfl_xor(a2, 32);
  a3 += __shfl_xor(a3, 32);
  if (rowsel == 0) {
    float4 bv = ((const float4*)bias)[cp];
    float4 o;
    o.x = a0 + bv.x; o.y = a1 + bv.y; o.z = a2 + bv.z; o.w = a3 + bv.w;
    ((float4*)(out + (size_t)d * OUT_F))[cp] = o;
  }
}

extern "C" void kernel_launch(void* const* d_in, const int* in_sizes, int n_in,
                              void* d_out, int out_size, void* d_ws, size_t ws_size,
                              hipStream_t stream) {
  const float* feat = (const float*)d_in[0];
  const float* weight = (const float*)d_in[1];
  const float* bias = (const float*)d_in[2];
  const int* src = (const int*)d_in[3];
  const int* dst = (const int*)d_in[4];
  float* out = (float*)d_out;

  char* ws = (char*)d_ws;
  size_t off = 0;
  auto alloc = [&](size_t bytes) -> void* {
    void* p = ws + off;
    off += (bytes + 511) & ~(size_t)511;
    return p;
  };
  int* cursor = (int*)alloc(4);
  int* cnt = (int*)alloc(N_NODES * 4);
  int* row_start = (int*)alloc(N_NODES * 4);
  float* norm = (float*)alloc(N_NODES * 4);
  int* eidx = (int*)alloc(N_EDGES * 4);
  short* Wf = (short*)alloc(IN_F * OUT_F * 2);
  unsigned short* h = (unsigned short*)alloc((size_t)N_NODES * OUT_F * 2);
  unsigned char* pdst8 = (unsigned char*)alloc((size_t)CHUNKS * N_NODES);
  unsigned char* psrc8 = (unsigned char*)alloc((size_t)CHUNKS * N_NODES);
  unsigned char* delta8 = (unsigned char*)alloc((size_t)CHUNKS * N_NODES);
  unsigned char* rank8 = (unsigned char*)alloc((size_t)N_EDGES);
  (void)off; (void)ws_size; (void)in_sizes; (void)n_in; (void)out_size;

  hipLaunchKernelGGL(hist_kernel, dim3(HIST_BLOCKS + 2), dim3(512), 0, stream,
                     src, dst, pdst8, psrc8, rank8, weight, Wf, cursor);
  hipLaunchKernelGGL(reduceoff_kernel, dim3(RGB, 2), dim3(256), 0, stream,
                     pdst8, psrc8, delta8, cnt, row_start, cursor, norm);
  hipLaunchKernelGGL(scat_kernel, dim3(SCAT_BLOCKS), dim3(256), 0, stream,
                     src, dst, row_start, delta8, rank8, eidx);
  hipLaunchKernelGGL(gemm_kernel, dim3(GEMM_BLOCKS), dim3(256), 0, stream,
                     feat, Wf, norm, h);
  hipLaunchKernelGGL(agg_kernel, dim3(N_NODES / 4), dim3(256), 0, stream, h, row_start, cnt, eidx, bias, out);
}

// Round 5
// 170.651 us; speedup vs baseline: 1.0780x; 1.0780x over previous
//
#include <hip/hip_runtime.h>

#define N_NODES 50000
#define N_EDGES 800000
#define IN_F 256
#define OUT_F 128

#define CHUNKS 128
#define EPC (N_EDGES / CHUNKS)   // 6250 edges per chunk
#define BINW (N_NODES / 4)       // 12500 u32 words, 4 x u8 bins each (50 KB LDS)
#define NWORDS (N_NODES / 4)     // 12500 packed node-words
#define RGB 196                  // reduceoff blocks: 64 words (256 nodes) each
#define HIST_BLOCKS (2 * CHUNKS) // 256
#define CPW (CHUNKS / 4)         // 32 chunks per wave

#define GEMM_START HIST_BLOCKS   // gemm blocks start after hist blocks in K1
#define GEMMF_BLOCKS 196         // 256 rows each -> 50176 >= 50000
#define SCAT_BLOCKS 782          // 1024 edges each -> 800768 >= 800000

typedef __attribute__((ext_vector_type(8))) short short8;
typedef __attribute__((ext_vector_type(4))) float float4_t;

// float -> bf16 round-to-nearest-even
__device__ __forceinline__ short f2bf(float f) {
  unsigned u = __builtin_bit_cast(unsigned, f);
  u = u + 0x7FFFu + ((u >> 16) & 1u);
  return (short)(u >> 16);
}

__device__ __forceinline__ float bflo(unsigned u) {
  return __builtin_bit_cast(float, u << 16);
}
__device__ __forceinline__ float bfhi(unsigned u) {
  return __builtin_bit_cast(float, u & 0xFFFF0000u);
}

// ---- K1: fused dst-hist + src-hist + GEMM (norm deferred to agg) ----
// blocks [0,128): dst-side hist + per-edge rank; [128,256): src-side hist;
// blocks [256, 256+196): h = feat @ W (bf16 MFMA), W staged f32->bf16 into LDS
// per block. GEMM depends only on feat/W, so it runs concurrent with the
// hist critical path — its serial time vanishes.
__global__ __launch_bounds__(512) void fused1_kernel(const int* __restrict__ src,
                                                     const int* __restrict__ dst,
                                                     unsigned char* __restrict__ pdst8,
                                                     unsigned char* __restrict__ psrc8,
                                                     unsigned char* __restrict__ rank8,
                                                     const float* __restrict__ W,
                                                     const float* __restrict__ feat,
                                                     unsigned short* __restrict__ h,
                                                     int* __restrict__ cursor) {
  __shared__ uint4 smem4[4096];  // 64 KB: hist bins (50 KB) or W-bf16 (64 KB)
  int b = blockIdx.x;
  int tid = threadIdx.x;

  if (b >= GEMM_START) {
    // ---- GEMM path ----
    if (b == GEMM_START && tid == 0) *cursor = 0;  // consumed by reduceoff (next kernel)
    short* wl = (short*)smem4;
    // stage W: lane-ordered fragment layout -> contiguous 1KB per wave ds_read
    // (k,n): s=k>>5,q=(k>>3)&3,j=k&7; tt=n>>4,m=n&15; frag S=s*8+tt, lane l=q*16+m
#pragma unroll
    for (int i = 0; i < 64; ++i) {
      int idx = i * 512 + tid;
      int k = idx >> 7, n = idx & 127;
      int s = k >> 5, q = (k >> 3) & 3, j = k & 7;
      int tt = n >> 4, m = n & 15;
      wl[((s * 8 + tt) * 64 + q * 16 + m) * 8 + j] = f2bf(W[idx]);
    }
    __syncthreads();

    int w = tid >> 6, l = tid & 63;
    int m = l & 15, q = l >> 4;
    long base = (long)(b - GEMM_START) * 256 + w * 32;

    float4_t acc[2][8];
#pragma unroll
    for (int r = 0; r < 2; ++r)
#pragma unroll
      for (int to = 0; to < 8; ++to) acc[r][to] = (float4_t)(0.0f);

    long row0 = base + m;
    long row1 = base + 16 + m;
    long r0c = row0 < N_NODES - 1 ? row0 : N_NODES - 1;
    long r1c = row1 < N_NODES - 1 ? row1 : N_NODES - 1;
    const float* a0p = feat + (size_t)r0c * IN_F;
    const float* a1p = feat + (size_t)r1c * IN_F;
    const short8* wl8 = (const short8*)smem4;

#pragma unroll
    for (int s = 0; s < 8; ++s) {
      int k0 = s * 32 + q * 8;
      float4_t av0a = *(const float4_t*)(a0p + k0);
      float4_t av0b = *(const float4_t*)(a0p + k0 + 4);
      float4_t av1a = *(const float4_t*)(a1p + k0);
      float4_t av1b = *(const float4_t*)(a1p + k0 + 4);
      short8 fa0, fa1;
#pragma unroll
      for (int i = 0; i < 4; ++i) {
        fa0[i] = f2bf(av0a[i]);
        fa0[i + 4] = f2bf(av0b[i]);
        fa1[i] = f2bf(av1a[i]);
        fa1[i + 4] = f2bf(av1b[i]);
      }
#pragma unroll
      for (int to = 0; to < 8; ++to) {
        short8 fb = wl8[(s * 8 + to) * 64 + l];
        acc[0][to] = __builtin_amdgcn_mfma_f32_16x16x32_bf16(fa0, fb, acc[0][to], 0, 0, 0);
        acc[1][to] = __builtin_amdgcn_mfma_f32_16x16x32_bf16(fa1, fb, acc[1][to], 0, 0, 0);
      }
    }

    // C/D layout: col = lane&15 (=m), row = q*4 + i. No norm here (deferred to agg).
#pragma unroll
    for (int r = 0; r < 2; ++r) {
#pragma unroll
      for (int i = 0; i < 4; ++i) {
        long row = base + r * 16 + q * 4 + i;
        if (row < N_NODES) {
          size_t ho = (size_t)row * OUT_F;
#pragma unroll
          for (int to = 0; to < 8; ++to) {
            h[ho + to * 16 + m] = (unsigned short)f2bf(acc[r][to][i]);
          }
        }
      }
    }
    return;
  }

  // ---- hist path (unchanged from verified R4 version) ----
  unsigned* bins = (unsigned*)smem4;
  int hs = b >> 7;
  int c = b & 127;
  uint4* b4 = (uint4*)bins;
  for (int j = tid; j < BINW / 4; j += 512) b4[j] = (uint4){0u, 0u, 0u, 0u};
  __syncthreads();
  const int* key = hs ? src : dst;
  int e0 = c * EPC;

  auto process = [&](int v, int eI) {
    unsigned sh = (v & 3) * 8;
    unsigned old = atomicAdd(&bins[v >> 2], 1u << sh);
    if (!hs) rank8[eI] = (unsigned char)((old >> sh) & 0xFFu);
  };

  // 3 full tiles of 2048 + tail of 106 (EPC = 6250)
#pragma unroll 2
  for (int tile = 0; tile < 3; ++tile) {
    int i = tile * 2048 + tid;
    int k0 = key[e0 + i];
    int k1 = key[e0 + i + 512];
    int k2 = key[e0 + i + 1024];
    int k3 = key[e0 + i + 1536];
    process(k0, e0 + i);
    process(k1, e0 + i + 512);
    process(k2, e0 + i + 1024);
    process(k3, e0 + i + 1536);
  }
  {
    int i = 6144 + tid;
    if (i < EPC) process(key[e0 + i], e0 + i);
  }
  __syncthreads();
  uint4* p128 = (uint4*)((hs ? psrc8 : pdst8) + (size_t)c * N_NODES);  // rows 16B-aligned
  const uint4* s128 = (const uint4*)bins;
  for (int j = tid; j < BINW / 4; j += 512) p128[j] = s128[j];
}

// grid (RGB, 2). Wave-split chunk prefix with packed-byte (4-node) arithmetic.
__global__ __launch_bounds__(256) void reduceoff_kernel(const unsigned char* __restrict__ pdst8,
                                                        const unsigned char* __restrict__ psrc8,
                                                        unsigned char* __restrict__ delta8,
                                                        int* __restrict__ cnt,
                                                        int* __restrict__ row_start,
                                                        int* __restrict__ cursor,
                                                        float* __restrict__ norm) {
  __shared__ unsigned tot[4][64];
  int g = blockIdx.x, side = blockIdx.y;
  int t = threadIdx.x;
  int w = t >> 6, l = t & 63;
  int wd = g * 64 + l;
  bool ok = wd < NWORDS;
  int wdc = ok ? wd : NWORDS - 1;  // clamp for safe addressing
  const unsigned* P = (const unsigned*)(side == 0 ? pdst8 : psrc8);

  unsigned vals[CPW];
  unsigned s = 0;
#pragma unroll
  for (int i = 0; i < CPW; ++i) {
    vals[i] = P[(size_t)(w * CPW + i) * NWORDS + wdc];
    s += vals[i];
  }
  tot[w][l] = s;
  __syncthreads();

  if (side == 0) {
    unsigned base = 0;
#pragma unroll
    for (int w2 = 0; w2 < 4; ++w2)
      if (w2 < w) base += tot[w2][l];
    unsigned run = base;
    unsigned* D = (unsigned*)delta8;
    if (ok) {
#pragma unroll
      for (int i = 0; i < CPW; ++i) {
        D[(size_t)(w * CPW + i) * NWORDS + wd] = run;
        run += vals[i];
      }
    }
    if (w == 0) {
      unsigned ftot = tot[0][l] + tot[1][l] + tot[2][l] + tot[3][l];
      if (!ok) ftot = 0;
      int c0 = ftot & 255, c1 = (ftot >> 8) & 255, c2 = (ftot >> 16) & 255, c3 = ftot >> 24;
      int T = c0 + c1 + c2 + c3;
      int x = T;
#pragma unroll
      for (int off = 1; off < 64; off <<= 1) {
        int y = __shfl_up(x, off);
        if (l >= off) x += y;
      }
      int waveTotal = __shfl(x, 63);
      int sb = 0;
      if (l == 63) sb = atomicAdd(cursor, waveTotal);
      sb = __shfl(sb, 63);
      int E = sb + x - T;
      if (ok) {
        int4 cv = {c0, c1, c2, c3};
        int4 rv = {E, E + c0, E + c0 + c1, E + c0 + c1 + c2};
        ((int4*)cnt)[wd] = cv;
        ((int4*)row_start)[wd] = rv;
      }
    }
  } else {
    if (w == 0 && ok) {
      unsigned ftot = tot[0][l] + tot[1][l] + tot[2][l] + tot[3][l];
      float4 nv;
      int d0 = ftot & 255, d1 = (ftot >> 8) & 255, d2 = (ftot >> 16) & 255, d3 = (int)(ftot >> 24);
      nv.x = 1.0f / (float)(d0 > 1 ? d0 : 1);
      nv.y = 1.0f / (float)(d1 > 1 ? d1 : 1);
      nv.z = 1.0f / (float)(d2 > 1 ? d2 : 1);
      nv.w = 1.0f / (float)(d3 > 1 ? d3 : 1);
      ((float4*)norm)[wd] = nv;
    }
  }
}

// ---- scatter: stateless, 4 edges/thread. ----
__global__ __launch_bounds__(256) void scat_kernel(const int* __restrict__ src,
                                                   const int* __restrict__ dst,
                                                   const int* __restrict__ row_start,
                                                   const unsigned char* __restrict__ delta8,
                                                   const unsigned char* __restrict__ rank8,
                                                   int* __restrict__ eidx) {
  int gt = blockIdx.x * 256 + threadIdx.x;
  int e = gt * 4;
  if (e >= N_EDGES) return;
  int4 d4 = *(const int4*)(dst + e);
  int4 s4 = *(const int4*)(src + e);
  unsigned rr = *(const unsigned*)(rank8 + e);
  int dd[4] = {d4.x, d4.y, d4.z, d4.w};
  int ss[4] = {s4.x, s4.y, s4.z, s4.w};
#pragma unroll
  for (int k = 0; k < 4; ++k) {
    int c = (e + k) / EPC;
    int d = dd[k];
    int pos = row_start[d] + (int)delta8[(size_t)c * N_NODES + d] + (int)((rr >> (8 * k)) & 0xFFu);
    eidx[pos] = ss[k];
  }
}

// One wave per dst node; norm applied here per gathered row (fma, norm[s] is a
// wave-broadcast load). This is what freed the GEMM from the reduceoff dependency.
__global__ __launch_bounds__(256) void agg_kernel(const unsigned short* __restrict__ h,
                                                  const int* __restrict__ row_start,
                                                  const int* __restrict__ cnt,
                                                  const int* __restrict__ eidx,
                                                  const float* __restrict__ norm,
                                                  const float* __restrict__ bias,
                                                  float* __restrict__ out) {
  int w = threadIdx.x >> 6, l = threadIdx.x & 63;
  int d = blockIdx.x * 4 + w;  // grid 12500 -> exactly 50000
  int rs = row_start[d], re = rs + cnt[d];
  const unsigned* __restrict__ hu = (const unsigned*)h;  // 64 uints per row
  int rowsel = l >> 5, cp = l & 31;  // lane covers cols 4*cp .. 4*cp+3
  float a0 = 0.f, a1 = 0.f, a2 = 0.f, a3 = 0.f;
  for (int bse = rs; bse < re; bse += 64) {
    int n = re - bse; if (n > 64) n = 64;
    int e = (l < n) ? eidx[bse + l] : 0;
    int half = (n + 1) >> 1;
    int j = 0;
    for (; j + 4 <= half; j += 4) {  // 8 rows per iteration, 4 gathers in flight
      int i0 = 2 * j + rowsel;
      int s0 = __shfl(e, i0);
      int s1 = __shfl(e, i0 + 2);
      int s2 = __shfl(e, i0 + 4);
      int s3 = __shfl(e, i0 + 6);
      uint2 v0 = *(const uint2*)(hu + (size_t)s0 * 64 + 2 * cp);
      uint2 v1 = *(const uint2*)(hu + (size_t)s1 * 64 + 2 * cp);
      uint2 v2 = *(const uint2*)(hu + (size_t)s2 * 64 + 2 * cp);
      uint2 v3 = *(const uint2*)(hu + (size_t)s3 * 64 + 2 * cp);
      float nm0 = norm[s0], nm1 = norm[s1], nm2 = norm[s2], nm3 = norm[s3];
      if (i0 >= n) { v0.x = 0; v0.y = 0; }
      if (i0 + 2 >= n) { v1.x = 0; v1.y = 0; }
      if (i0 + 4 >= n) { v2.x = 0; v2.y = 0; }
      if (i0 + 6 >= n) { v3.x = 0; v3.y = 0; }
      a0 = fmaf(bflo(v0.x), nm0, a0); a1 = fmaf(bfhi(v0.x), nm0, a1);
      a2 = fmaf(bflo(v0.y), nm0, a2); a3 = fmaf(bfhi(v0.y), nm0, a3);
      a0 = fmaf(bflo(v1.x), nm1, a0); a1 = fmaf(bfhi(v1.x), nm1, a1);
      a2 = fmaf(bflo(v1.y), nm1, a2); a3 = fmaf(bfhi(v1.y), nm1, a3);
      a0 = fmaf(bflo(v2.x), nm2, a0); a1 = fmaf(bfhi(v2.x), nm2, a1);
      a2 = fmaf(bflo(v2.y), nm2, a2); a3 = fmaf(bfhi(v2.y), nm2, a3);
      a0 = fmaf(bflo(v3.x), nm3, a0); a1 = fmaf(bfhi(v3.x), nm3, a1);
      a2 = fmaf(bflo(v3.y), nm3, a2); a3 = fmaf(bfhi(v3.y), nm3, a3);
    }
    for (; j + 2 <= half; j += 2) {
      int i0 = 2 * j + rowsel;
      int i1 = i0 + 2;
      int s0 = __shfl(e, i0);
      int s1 = __shfl(e, i1);
      uint2 v0 = *(const uint2*)(hu + (size_t)s0 * 64 + 2 * cp);
      uint2 v1 = *(const uint2*)(hu + (size_t)s1 * 64 + 2 * cp);
      float nm0 = norm[s0], nm1 = norm[s1];
      if (i0 >= n) { v0.x = 0; v0.y = 0; }
      if (i1 >= n) { v1.x = 0; v1.y = 0; }
      a0 = fmaf(bflo(v0.x), nm0, a0); a1 = fmaf(bfhi(v0.x), nm0, a1);
      a2 = fmaf(bflo(v0.y), nm0, a2); a3 = fmaf(bfhi(v0.y), nm0, a3);
      a0 = fmaf(bflo(v1.x), nm1, a0); a1 = fmaf(bfhi(v1.x), nm1, a1);
      a2 = fmaf(bflo(v1.y), nm1, a2); a3 = fmaf(bfhi(v1.y), nm1, a3);
    }
    for (; j < half; ++j) {
      int i0 = 2 * j + rowsel;
      int s0 = __shfl(e, i0);
      uint2 v0 = *(const uint2*)(hu + (size_t)s0 * 64 + 2 * cp);
      float nm0 = norm[s0];
      if (i0 >= n) { v0.x = 0; v0.y = 0; }
      a0 = fmaf(bflo(v0.x), nm0, a0); a1 = fmaf(bfhi(v0.x), nm0, a1);
      a2 = fmaf(bflo(v0.y), nm0, a2); a3 = fmaf(bfhi(v0.y), nm0, a3);
    }
  }
  a0 += __shfl_xor(a0, 32);
  a1 += __shfl_xor(a1, 32);
  a2 += __shfl_xor(a2, 32);
  a3 += __shfl_xor(a3, 32);
  if (rowsel == 0) {
    float4 bv = ((const float4*)bias)[cp];
    float4 o;
    o.x = a0 + bv.x; o.y = a1 + bv.y; o.z = a2 + bv.z; o.w = a3 + bv.w;
    ((float4*)(out + (size_t)d * OUT_F))[cp] = o;
  }
}

extern "C" void kernel_launch(void* const* d_in, const int* in_sizes, int n_in,
                              void* d_out, int out_size, void* d_ws, size_t ws_size,
                              hipStream_t stream) {
  const float* feat = (const float*)d_in[0];
  const float* weight = (const float*)d_in[1];
  const float* bias = (const float*)d_in[2];
  const int* src = (const int*)d_in[3];
  const int* dst = (const int*)d_in[4];
  float* out = (float*)d_out;

  char* ws = (char*)d_ws;
  size_t off = 0;
  auto alloc = [&](size_t bytes) -> void* {
    void* p = ws + off;
    off += (bytes + 511) & ~(size_t)511;
    return p;
  };
  int* cursor = (int*)alloc(4);
  int* cnt = (int*)alloc(N_NODES * 4);
  int* row_start = (int*)alloc(N_NODES * 4);
  float* norm = (float*)alloc(N_NODES * 4);
  int* eidx = (int*)alloc(N_EDGES * 4);
  unsigned short* h = (unsigned short*)alloc((size_t)N_NODES * OUT_F * 2);
  unsigned char* pdst8 = (unsigned char*)alloc((size_t)CHUNKS * N_NODES);
  unsigned char* psrc8 = (unsigned char*)alloc((size_t)CHUNKS * N_NODES);
  unsigned char* delta8 = (unsigned char*)alloc((size_t)CHUNKS * N_NODES);
  unsigned char* rank8 = (unsigned char*)alloc((size_t)N_EDGES);
  (void)off; (void)ws_size; (void)in_sizes; (void)n_in; (void)out_size;

  hipLaunchKernelGGL(fused1_kernel, dim3(HIST_BLOCKS + GEMMF_BLOCKS), dim3(512), 0, stream,
                     src, dst, pdst8, psrc8, rank8, weight, feat, h, cursor);
  hipLaunchKernelGGL(reduceoff_kernel, dim3(RGB, 2), dim3(256), 0, stream,
                     pdst8, psrc8, delta8, cnt, row_start, cursor, norm);
  hipLaunchKernelGGL(scat_kernel, dim3(SCAT_BLOCKS), dim3(256), 0, stream,
                     src, dst, row_start, delta8, rank8, eidx);
  hipLaunchKernelGGL(agg_kernel, dim3(N_NODES / 4), dim3(256), 0, stream,
                     h, row_start, cnt, eidx, norm, bias, out);
}